// Round 13
// baseline (144.781 us; speedup 1.0000x reference)
//
#include <hip/hip_runtime.h>
#include <math.h>
#include <stdint.h>

#define NB   16
#define NPT  2048
#define NF   512
#define BI   128
#define BJ   128
#define KB   32
#define NTHR 512
#define NJT  (NPT / BJ)   // 16
#define NIT  (NPT / BI)   // 16
#define NKC  (NF / KB)    // 16
#define NIQ  4            // i-quarters (512 rows each), main path

// ---- tiled fp16 HI-ONLY global layout (main path) ----
// per tensor: [b][kc][cg(128)] x 1024B; cg block = [hi kh0 | hi kh1] 512B
// windows; window = [kg(4)][j(4)][c(16)] fp16 (tr-read order, verified r3).
#define CGB1     1024
#define KCSLAB1  (128 * CGB1)                      // 128 KB per (b,kc)
#define TPB1     ((size_t)NB * NKC * KCSLAB1)      // 32 MB per tensor

// ---- fallback (round-4) padded LDS geometry (3-term hi/lo) ----
#define CGS    1056
#define PLANE  8448
#define PLANE_H 4224
#define BPLANE 16896
#define BUF2   50688

typedef _Float16 h4 __attribute__((ext_vector_type(4)));
typedef _Float16 h8 __attribute__((ext_vector_type(8)));
typedef float    f32x4 __attribute__((ext_vector_type(4)));

// ds_read_b64_tr_b16, NATURAL addressing (base + lane*8): 64 lanes cover a
// 512B [16k][16col] window; lane l gets col (l&15), k = 4*(l>>4)+j. [m156/m162]
#define TRR(dst, a) asm volatile("ds_read_b64_tr_b16 %0, %1" : "=v"(dst) : "v"(a))

#define MF(A, B, C) __builtin_amdgcn_mfma_f32_16x16x32_f16(A, B, C, 0, 0, 0)

__device__ __forceinline__ void gld16(const void* g, void* l) {
    __builtin_amdgcn_global_load_lds(
        (const __attribute__((address_space(1))) unsigned int*)g,
        (__attribute__((address_space(3))) unsigned int*)l, 16, 0, 0);
}

__device__ __forceinline__ h8 cat(h4 a, h4 b) {
    return __builtin_shufflevector(a, b, 0, 1, 2, 3, 4, 5, 6, 7);
}

__device__ __forceinline__ void cvt8(const float4 a, const float4 b, h8& hi, h8& lo) {
    hi[0] = (_Float16)a.x; hi[1] = (_Float16)a.y;
    hi[2] = (_Float16)a.z; hi[3] = (_Float16)a.w;
    hi[4] = (_Float16)b.x; hi[5] = (_Float16)b.y;
    hi[6] = (_Float16)b.z; hi[7] = (_Float16)b.w;
    lo[0] = (_Float16)(a.x - (float)hi[0]);
    lo[1] = (_Float16)(a.y - (float)hi[1]);
    lo[2] = (_Float16)(a.z - (float)hi[2]);
    lo[3] = (_Float16)(a.w - (float)hi[3]);
    lo[4] = (_Float16)(b.x - (float)hi[4]);
    lo[5] = (_Float16)(b.y - (float)hi[5]);
    lo[6] = (_Float16)(b.z - (float)hi[6]);
    lo[7] = (_Float16)(b.w - (float)hi[7]);
}

__device__ __forceinline__ h8 cvt8h(const float4 a, const float4 b) {
    h8 hi;
    hi[0] = (_Float16)a.x; hi[1] = (_Float16)a.y;
    hi[2] = (_Float16)a.z; hi[3] = (_Float16)a.w;
    hi[4] = (_Float16)b.x; hi[5] = (_Float16)b.y;
    hi[6] = (_Float16)b.z; hi[7] = (_Float16)b.w;
    return hi;
}

__device__ __forceinline__ int hoffB(int f, int n8) {
    return (n8 >> 1) * CGS + (f >> 4) * 512 + ((f >> 2) & 3) * 128
         + (f & 3) * 32 + (n8 & 1) * 16;
}

// ---------------------------------------------------------------------------
// Prepass: fp32 -> tiled fp16 HI-ONLY (tr-window byte order). Unchanged r11.
// ---------------------------------------------------------------------------
__global__ __launch_bounds__(256)
void prepass_kernel(const float* __restrict__ fsource,
                    const float* __restrict__ ftarget,
                    _Float16* __restrict__ tiled)
{
    const int b  = blockIdx.x;
    const int kc = blockIdx.y;
    const int z  = blockIdx.z;            // tensor(2) x cgrp(8)
    const int tensor = z >> 3;
    const int cgrp   = z & 7;
    const float* src = (tensor == 0 ? ftarget : fsource)
                     + (size_t)b * NF * NPT + (size_t)kc * KB * NPT + cgrp * 256;
    char* dst = (char*)tiled + (size_t)tensor * TPB1
              + ((size_t)(b * NKC + kc) * 128 + cgrp * 16) * CGB1;

    __shared__ _Float16 sm[8448];         // 16 cg x 1056B (pad +32B)
    const int t   = threadIdx.x;
    const int kk8 = t >> 5;               // 0..7
    const int c8  = (t & 31) * 8;         // 0..248
    const int cg  = c8 >> 4;
    const int cl  = c8 & 15;              // 0 or 8

    #pragma unroll
    for (int rep = 0; rep < 4; ++rep) {
        const int k = rep * 8 + kk8;      // 0..31
        const float4 v0 = *(const float4*)(src + (size_t)k * NPT + c8);
        const float4 v1 = *(const float4*)(src + (size_t)k * NPT + c8 + 4);
        const h8 hi = cvt8h(v0, v1);
        const int kh = k >> 4, kr = k & 15, kg = kr >> 2, j = kr & 3;
        *(h8*)((char*)sm + cg * 1056 + kh * 512 + kg * 128 + j * 32 + cl * 2) = hi;
    }
    __syncthreads();
    #pragma unroll
    for (int q = 0; q < 4; ++q) {
        const int off = q * 4096 + t * 16;         // 16 KB, lanes contiguous
        const int ocg = off >> 10, rem = off & 1023;
        *(float4*)(dst + off) = *(const float4*)((char*)sm + ocg * 1056 + rem);
    }
}

// ---------------------------------------------------------------------------
// Main GEMM kernel (round-13): BK=64 steps (two kc-slabs per pipeline step)
// -> half the barriers / vmcnt waits / address setups of r12. Double-buffered
// 32 KB stages; 8 DMAs/thread issued at step top (issue->wait distance = one
// ~2000cy step, covers HBM miss). Compute = proven 6/4/2/0 ladder x2 halves.
// LDS 75 KB -> 2 blocks/CU. Grid (16 b, 16 jt, 4 iq) = 1024 blocks.
// ---------------------------------------------------------------------------
__global__ __launch_bounds__(256, 2)
void attn_state_tiled(const float* __restrict__ target,
                      const _Float16* __restrict__ tiled,
                      float* __restrict__ stw)    // [5][16*4*2048]
{
    const int b    = blockIdx.x;
    const int jt   = blockIdx.y;          // 0..15
    const int iq   = blockIdx.z;          // 0..3
    const int j0   = jt * BJ;
    const int tid  = threadIdx.x;
    const int lane = tid & 63;
    const int wave = tid >> 6;            // 0..3
    const int wi   = wave >> 1;           // 0..1: rows [wi*64, +64)
    const int wj   = wave & 1;            // 0..1: cols [wj*64, +64)
    const int lg   = lane >> 4;
    const int lr   = lane & 15;

    // per buf (32 KB): A_even @0, A_odd @8192, B_even @16384, B_odd @24576
    __shared__ __align__(16) char TIL[2][32768];
    __shared__ float  tgtsAll[3][512];            // all 512 i-rows of this block
    __shared__ float  redM[2][BJ];
    __shared__ float4 redS[2][BJ];

    const uint32_t tilesBase = (uint32_t)(uintptr_t)&TIL[0][0];
    const uint32_t trLane    = (uint32_t)(lane * 8);

    const char* Atile = (const char*)tiled;          // ftarget tiled (hi)
    const char* Btile = (const char*)tiled + TPB1;   // fsource tiled (hi)

    // ---- once: preload target coords for the block's 512 i-rows ----
    {
        const float* tg = target + ((size_t)b * NPT + iq * 512) * 3;
        #pragma unroll
        for (int k = 0; k < 6; ++k) {
            const int p = tid + k * 256;   // 0..1535 = row*3 + c
            tgtsAll[p % 3][p / 3] = tg[p];
        }
    }
    __syncthreads();

    float Mrun[4], Zrun[4], Yrun[4][3];
    #pragma unroll
    for (int n = 0; n < 4; ++n) {
        Mrun[n] = -3.0e38f; Zrun[n] = 0.0f;
        Yrun[n][0] = 0.0f; Yrun[n][1] = 0.0f; Yrun[n][2] = 0.0f;
    }

#define STAGE2(kc2v, dstbuf) { \
    const size_t slab0 = (size_t)(b * NKC + 2 * (kc2v)) * KCSLAB1; \
    const size_t slab1 = slab0 + KCSLAB1; \
    const size_t aoff  = (size_t)(i0 >> 4) * CGB1 + lane * 16; \
    const size_t boff  = (size_t)(j0 >> 4) * CGB1 + lane * 16; \
    char* lb = &TIL[dstbuf][0]; \
    gld16(Atile + slab0 + aoff + wave * 1024,       lb + wave * 1024); \
    gld16(Atile + slab0 + aoff + (wave + 4) * 1024, lb + (wave + 4) * 1024); \
    gld16(Atile + slab1 + aoff + wave * 1024,       lb + 8192 + wave * 1024); \
    gld16(Atile + slab1 + aoff + (wave + 4) * 1024, lb + 8192 + (wave + 4) * 1024); \
    gld16(Btile + slab0 + boff + wave * 1024,       lb + 16384 + wave * 1024); \
    gld16(Btile + slab0 + boff + (wave + 4) * 1024, lb + 16384 + (wave + 4) * 1024); \
    gld16(Btile + slab1 + boff + wave * 1024,       lb + 24576 + wave * 1024); \
    gld16(Btile + slab1 + boff + (wave + 4) * 1024, lb + 24576 + (wave + 4) * 1024); }

#define RD_A1(m) TRR(ta[m][0], aB + (m) * CGB1); \
                 TRR(ta[m][1], aB + (m) * CGB1 + 512);
#define RD_B1(n) TRR(tb[n][0], bB + (n) * CGB1); \
                 TRR(tb[n][1], bB + (n) * CGB1 + 512);
#define WAITK(N) asm volatile("s_waitcnt lgkmcnt(" #N ")" ::: "memory"); \
                 __builtin_amdgcn_sched_barrier(0);
#define MROW1(M) \
    { const h8 Ah = cat(ta[M][0], ta[M][1]); \
      acc[M][0] = MF(Ah, Bh[0], acc[M][0]); \
      acc[M][1] = MF(Ah, Bh[1], acc[M][1]); \
      acc[M][2] = MF(Ah, Bh[2], acc[M][2]); \
      acc[M][3] = MF(Ah, Bh[3], acc[M][3]); }

// One K=32 half: 16 tr-reads + 16 MFMAs with the proven 6/4/2/0 ladder.
#define KHALF(hofs) { \
    const uint32_t aB = bufB + (hofs) + (uint32_t)(wi * 4) * CGB1 + trLane; \
    const uint32_t bB = bufB + 16384u + (hofs) + (uint32_t)(wj * 4) * CGB1 + trLane; \
    h4 ta[4][2], tb[4][2]; \
    h8 Bh[4]; \
    RD_A1(0) RD_B1(0) RD_B1(1) RD_B1(2) RD_B1(3) \
    RD_A1(1) RD_A1(2) RD_A1(3) \
    WAITK(6) \
    Bh[0] = cat(tb[0][0], tb[0][1]); \
    Bh[1] = cat(tb[1][0], tb[1][1]); \
    Bh[2] = cat(tb[2][0], tb[2][1]); \
    Bh[3] = cat(tb[3][0], tb[3][1]); \
    MROW1(0) \
    WAITK(4) MROW1(1) \
    WAITK(2) MROW1(2) \
    WAITK(0) MROW1(3) }

    for (int it = 0; it < 4; ++it) {
        const int i0 = iq * 512 + it * BI;

        // ---- prologue: stage step 0 into buf0 ----
        STAGE2(0, 0)
        asm volatile("s_waitcnt vmcnt(0)" ::: "memory");
        __builtin_amdgcn_sched_barrier(0);
        __syncthreads();

        f32x4 acc[4][4];
        #pragma unroll
        for (int m = 0; m < 4; ++m)
            #pragma unroll
            for (int n = 0; n < 4; ++n)
                acc[m][n] = (f32x4){0.0f, 0.0f, 0.0f, 0.0f};

        for (int kc2 = 0; kc2 < 8; ++kc2) {
            const int buf = kc2 & 1;
            // prefetch next BK=64 step; lands under this step's ~2000cy compute
            if (kc2 + 1 < 8) STAGE2(kc2 + 1, buf ^ 1)

            const uint32_t bufB = tilesBase + (uint32_t)buf * 32768;
            __builtin_amdgcn_s_setprio(1);
            KHALF(0u)
            KHALF(8192u)
            __builtin_amdgcn_s_setprio(0);

            asm volatile("s_waitcnt vmcnt(0)" ::: "memory");
            __builtin_amdgcn_sched_barrier(0);
            __syncthreads();
        }

        // ---- online softmax update for this i-tile ----
        // D layout: col j = wj*64 + n*16 + lr, row i = wi*64 + m*16 + lg*4 + r
        #pragma unroll
        for (int n = 0; n < 4; ++n) {
            float m = acc[0][n][0];
            #pragma unroll
            for (int mm = 0; mm < 4; ++mm)
                #pragma unroll
                for (int r = 0; r < 4; ++r)
                    m = fmaxf(m, acc[mm][n][r]);
            m = fmaxf(m, __shfl_xor(m, 16));
            m = fmaxf(m, __shfl_xor(m, 32));
            if (lane < 16) redM[wi][wj * 64 + n * 16 + lr] = m;
        }
        __syncthreads();
        float mnew[4];
        #pragma unroll
        for (int n = 0; n < 4; ++n) {
            const int col = wj * 64 + n * 16 + lr;
            mnew[n] = fmaxf(Mrun[n], fmaxf(redM[0][col], redM[1][col]));
        }

        float z[4] = {0, 0, 0, 0}, y[4][3] = {{0,0,0},{0,0,0},{0,0,0},{0,0,0}};
        #pragma unroll
        for (int mm = 0; mm < 4; ++mm)
            #pragma unroll
            for (int r = 0; r < 4; ++r) {
                const int iL = it * BI + wi * 64 + mm * 16 + lg * 4 + r;
                const float t0 = tgtsAll[0][iL], t1 = tgtsAll[1][iL], t2 = tgtsAll[2][iL];
                #pragma unroll
                for (int n = 0; n < 4; ++n) {
                    const float e = __expf(acc[mm][n][r] - mnew[n]);
                    z[n] += e;
                    y[n][0] = fmaf(e, t0, y[n][0]);
                    y[n][1] = fmaf(e, t1, y[n][1]);
                    y[n][2] = fmaf(e, t2, y[n][2]);
                }
            }
        #pragma unroll
        for (int n = 0; n < 4; ++n) {
            #pragma unroll
            for (int off = 16; off <= 32; off <<= 1) {
                z[n]    += __shfl_xor(z[n], off);
                y[n][0] += __shfl_xor(y[n][0], off);
                y[n][1] += __shfl_xor(y[n][1], off);
                y[n][2] += __shfl_xor(y[n][2], off);
            }
            if (lane < 16)
                redS[wi][wj * 64 + n * 16 + lr] = make_float4(z[n], y[n][0], y[n][1], y[n][2]);
        }
        __syncthreads();
        #pragma unroll
        for (int n = 0; n < 4; ++n) {
            const int col = wj * 64 + n * 16 + lr;
            const float4 s0 = redS[0][col], s1 = redS[1][col];
            const float sc = __expf(Mrun[n] - mnew[n]);
            Zrun[n]    = Zrun[n]    * sc + s0.x + s1.x;
            Yrun[n][0] = Yrun[n][0] * sc + s0.y + s1.y;
            Yrun[n][1] = Yrun[n][1] * sc + s0.z + s1.z;
            Yrun[n][2] = Yrun[n][2] * sc + s0.w + s1.w;
            Mrun[n] = mnew[n];
        }
        __syncthreads();   // protect redM/redS/TIL before next it's staging
    }

    // ---- write per-column state ----
    if (wi == 0 && lane < 16) {
        const int SP4 = NB * NIQ * NPT;
        #pragma unroll
        for (int n = 0; n < 4; ++n) {
            const int j   = j0 + wj * 64 + n * 16 + lr;
            const int idx = (b * NIQ + iq) * NPT + j;
            stw[idx]           = Mrun[n];
            stw[SP4 + idx]     = Zrun[n];
            stw[2 * SP4 + idx] = Yrun[n][0];
            stw[3 * SP4 + idx] = Yrun[n][1];
            stw[4 * SP4 + idx] = Yrun[n][2];
        }
    }
#undef STAGE2
#undef RD_A1
#undef RD_B1
#undef WAITK
#undef MROW1
#undef KHALF
}

// ---------------------------------------------------------------------------
// Combine (main path): merge the 4 i-quarter softmax states per column,
// compute pred, per-(b, 128-j-chunk) partial sums (15 values).
// ---------------------------------------------------------------------------
__global__ void combine4_kernel(const float* __restrict__ source,
                                const float* __restrict__ stw,
                                float* __restrict__ partials)
{
    const int b   = blockIdx.x;
    const int jc  = blockIdx.y;     // 0..15
    const int tid = threadIdx.x;    // 128
    const int lane = tid & 63, wv = tid >> 6;
    const int j = jc * BJ + tid;
    const int SP = NB * NIQ * NPT;

    __shared__ float fin2[2][15];

    float m[NIQ], zz[NIQ], yy0[NIQ], yy1[NIQ], yy2[NIQ];
    #pragma unroll
    for (int q = 0; q < NIQ; ++q) {
        const int idx = (b * NIQ + q) * NPT + j;
        m[q]   = stw[idx];
        zz[q]  = stw[SP + idx];
        yy0[q] = stw[2 * SP + idx];
        yy1[q] = stw[3 * SP + idx];
        yy2[q] = stw[4 * SP + idx];
    }
    float ms = m[0];
    #pragma unroll
    for (int q = 1; q < NIQ; ++q) ms = fmaxf(ms, m[q]);
    float Z = 0, Y0 = 0, Y1 = 0, Y2 = 0;
    #pragma unroll
    for (int q = 0; q < NIQ; ++q) {
        const float s = __expf(m[q] - ms);
        Z  += zz[q]  * s;
        Y0 += yy0[q] * s;
        Y1 += yy1[q] * s;
        Y2 += yy2[q] * s;
    }
    const float iz = 1.0f / Z;
    const float p0 = Y0 * iz, p1 = Y1 * iz, p2 = Y2 * iz;

    const float* sp = source + ((size_t)b * NPT + j) * 3;
    const float s0 = sp[0], s1 = sp[1], s2 = sp[2];

    float v[15];
    v[0] = s0; v[1] = s1; v[2] = s2;
    v[3] = p0; v[4] = p1; v[5] = p2;
    v[6]  = s0 * p0; v[7]  = s0 * p1; v[8]  = s0 * p2;
    v[9]  = s1 * p0; v[10] = s1 * p1; v[11] = s1 * p2;
    v[12] = s2 * p0; v[13] = s2 * p1; v[14] = s2 * p2;

    #pragma unroll
    for (int q = 0; q < 15; ++q)
        #pragma unroll
        for (int off = 32; off > 0; off >>= 1)
            v[q] += __shfl_down(v[q], off);
    if (lane == 0) {
        #pragma unroll
        for (int q = 0; q < 15; ++q) fin2[wv][q] = v[q];
    }
    __syncthreads();
    if (tid == 0) {
        float* o = partials + (((size_t)b << 4) + jc) * 16;
        #pragma unroll
        for (int q = 0; q < 15; ++q) o[q] = fin2[0][q] + fin2[1][q];
    }
}

// ---------------------------------------------------------------------------
// Combine (fallback): merge two i-half states (round-7 code).
// ---------------------------------------------------------------------------
__global__ void combine_kernel(const float* __restrict__ source,
                               const float* __restrict__ stw,
                               float* __restrict__ partials)
{
    const int b   = blockIdx.x;
    const int jc  = blockIdx.y;
    const int tid = threadIdx.x;    // 128
    const int lane = tid & 63, wv = tid >> 6;
    const int j = jc * BJ + tid;
    const int SP = NB * 2 * NPT;
    const int i0 = (b * 2 + 0) * NPT + j;
    const int i1 = (b * 2 + 1) * NPT + j;

    __shared__ float fin2[2][15];

    const float ma = stw[i0],      mb = stw[i1];
    const float za = stw[SP + i0], zb = stw[SP + i1];
    const float ms = fmaxf(ma, mb);
    const float sa = __expf(ma - ms), sb = __expf(mb - ms);
    const float zt = za * sa + zb * sb;
    const float iz = 1.0f / zt;
    const float p0 = (stw[2 * SP + i0] * sa + stw[2 * SP + i1] * sb) * iz;
    const float p1 = (stw[3 * SP + i0] * sa + stw[3 * SP + i1] * sb) * iz;
    const float p2 = (stw[4 * SP + i0] * sa + stw[4 * SP + i1] * sb) * iz;

    const float* sp = source + ((size_t)b * NPT + j) * 3;
    const float s0 = sp[0], s1 = sp[1], s2 = sp[2];

    float v[15];
    v[0] = s0; v[1] = s1; v[2] = s2;
    v[3] = p0; v[4] = p1; v[5] = p2;
    v[6]  = s0 * p0; v[7]  = s0 * p1; v[8]  = s0 * p2;
    v[9]  = s1 * p0; v[10] = s1 * p1; v[11] = s1 * p2;
    v[12] = s2 * p0; v[13] = s2 * p1; v[14] = s2 * p2;

    #pragma unroll
    for (int q = 0; q < 15; ++q)
        #pragma unroll
        for (int off = 32; off > 0; off >>= 1)
            v[q] += __shfl_down(v[q], off);
    if (lane == 0) {
        #pragma unroll
        for (int q = 0; q < 15; ++q) fin2[wv][q] = v[q];
    }
    __syncthreads();
    if (tid == 0) {
        float* o = partials + (((size_t)b << 4) + jc) * 16;
        #pragma unroll
        for (int q = 0; q < 15; ++q) o[q] = fin2[0][q] + fin2[1][q];
    }
}

// ---------------------------------------------------------------------------
// Fallback (round-4 proven, 3-term hi/lo): in-loop cvt staging.
// ---------------------------------------------------------------------------
__global__ __launch_bounds__(NTHR, 2)
void attn_state_kernel(const float* __restrict__ target,
                       const float* __restrict__ fsource,
                       const float* __restrict__ ftarget,
                       float* __restrict__ stw)
{
    const int b    = blockIdx.x;
    const int jt   = blockIdx.y;
    const int ih   = blockIdx.z;
    const int j0   = jt * 256;
    const int tid  = threadIdx.x;
    const int lane = tid & 63;
    const int wave = tid >> 6;
    const int wi   = wave >> 2;
    const int wj   = wave & 3;
    const int lg   = lane >> 4;
    const int lr   = lane & 15;

    __shared__ __align__(16) unsigned char TIL[2][BUF2];
    __shared__ float  tgts[3][BI];
    __shared__ float  redM[2][256];
    __shared__ float4 redS[2][256];

    const uint32_t tilesBase = (uint32_t)(uintptr_t)&TIL[0][0];
    const uint32_t trLane    = (uint32_t)(lane * 8);
    const size_t   fbase     = (size_t)b * NF * NPT;

    const int fA  = tid >> 4,  n8A  = tid & 15;
    const int fB0 = tid >> 5,  n8B  = tid & 31;
    const int fB1 = (tid + 512) >> 5;
    const int offA  = hoffB(fA, n8A);
    const int offB0 = hoffB(fB0, n8B);
    const int offB1 = hoffB(fB1, n8B);

    float Mrun[4], Zrun[4], Yrun[4][3];
    #pragma unroll
    for (int n = 0; n < 4; ++n) {
        Mrun[n] = -3.0e38f; Zrun[n] = 0.0f;
        Yrun[n][0] = 0.0f; Yrun[n][1] = 0.0f; Yrun[n][2] = 0.0f;
    }

#define RD_B(n) TRR(tb[n][0][0], bB + (n) * CGS); \
                TRR(tb[n][0][1], bB + (n) * CGS + 512); \
                TRR(tb[n][1][0], bB + (n) * CGS + BPLANE); \
                TRR(tb[n][1][1], bB + (n) * CGS + BPLANE + 512);
#define RD_A(m) TRR(ta[m][0][0], aB + (m) * CGS); \
                TRR(ta[m][0][1], aB + (m) * CGS + 512); \
                TRR(ta[m][1][0], aB + (m) * CGS + PLANE); \
                TRR(ta[m][1][1], aB + (m) * CGS + PLANE + 512);
#define BBLD(n) Bh[n] = cat(tb[n][0][0], tb[n][0][1]); \
                Bl[n] = cat(tb[n][1][0], tb[n][1][1]);
#define MM3(M, N) \
    acc[M][N] = MF(Ah, Bh[N], acc[M][N]); \
    acc[M][N] = MF(Ah, Bl[N], acc[M][N]); \
    acc[M][N] = MF(Al, Bh[N], acc[M][N]);
#define MSTEP(M, WAITSTR) \
    asm volatile("s_waitcnt lgkmcnt(" WAITSTR ")" ::: "memory"); \
    __builtin_amdgcn_sched_barrier(0); \
    { const h8 Ah = cat(ta[M][0][0], ta[M][0][1]); \
      const h8 Al = cat(ta[M][1][0], ta[M][1][1]); \
      MM3(M, 0) MM3(M, 1) MM3(M, 2) MM3(M, 3) }

    for (int it = 0; it < 8; ++it) {
        const int i0 = ih * 1024 + it * BI;

        const float* pA  = ftarget + fbase + (size_t)fA  * NPT + i0 + n8A * 8;
        const float* pB0 = fsource + fbase + (size_t)fB0 * NPT + j0 + n8B * 8;
        const float* pB1 = fsource + fbase + (size_t)fB1 * NPT + j0 + n8B * 8;

        {
            float4 a0  = *(const float4*)(pA);
            float4 a1  = *(const float4*)(pA + 4);
            float4 b00 = *(const float4*)(pB0);
            float4 b01 = *(const float4*)(pB0 + 4);
            float4 b10 = *(const float4*)(pB1);
            float4 b11 = *(const float4*)(pB1 + 4);
            if (tid < BI) {
                const float* tp = target + ((size_t)b * NPT + i0 + tid) * 3;
                tgts[0][tid] = tp[0]; tgts[1][tid] = tp[1]; tgts[2][tid] = tp[2];
            }
            unsigned char* bp = (unsigned char*)&TIL[0][0];
            h8 hi, lo;
            cvt8(a0, a1, hi, lo);
            *(h8*)(bp + offA) = hi;  *(h8*)(bp + PLANE + offA) = lo;
            cvt8(b00, b01, hi, lo);
            *(h8*)(bp + 2 * PLANE + offB0) = hi;  *(h8*)(bp + 2 * PLANE + BPLANE + offB0) = lo;
            cvt8(b10, b11, hi, lo);
            *(h8*)(bp + 2 * PLANE + offB1) = hi;  *(h8*)(bp + 2 * PLANE + BPLANE + offB1) = lo;
        }
        __syncthreads();

        f32x4 acc[4][4];
        #pragma unroll
        for (int m = 0; m < 4; ++m)
            #pragma unroll
            for (int n = 0; n < 4; ++n)
                acc[m][n] = (f32x4){0.0f, 0.0f, 0.0f, 0.0f};

        for (int kc = 0; kc < NKC; ++kc) {
            const int buf = kc & 1;
            float4 ga0, ga1, gb00, gb01, gb10, gb11;
            if (kc + 1 < NKC) {
                const size_t ko = (size_t)(kc + 1) * KB * NPT;
                ga0  = *(const float4*)(pA + ko);
                ga1  = *(const float4*)(pA + ko + 4);
                gb00 = *(const float4*)(pB0 + ko);
                gb01 = *(const float4*)(pB0 + ko + 4);
                gb10 = *(const float4*)(pB1 + ko);
                gb11 = *(const float4*)(pB1 + ko + 4);
            }

            const uint32_t bb = tilesBase + (uint32_t)buf * BUF2;
            const uint32_t aB = bb + (uint32_t)(wi * 4) * CGS + trLane;
            const uint32_t bB = bb + 2u * PLANE + (uint32_t)(wj * 4) * CGS + trLane;
            h4 ta[4][2][2], tb[4][2][2];
            h8 Bh[4], Bl[4];

            __builtin_amdgcn_s_setprio(1);
            RD_B(0) RD_B(1) RD_B(2) RD_B(3)
            RD_A(0) RD_A(1) RD_A(2) RD_A(3)
            asm volatile("s_waitcnt lgkmcnt(12)" ::: "memory");
            __builtin_amdgcn_sched_barrier(0);
            BBLD(0) BBLD(1) BBLD(2) BBLD(3)
            {
                const h8 Ah = cat(ta[0][0][0], ta[0][0][1]);
                const h8 Al = cat(ta[0][1][0], ta[0][1][1]);
                MM3(0, 0) MM3(0, 1) MM3(0, 2) MM3(0, 3)
            }
            MSTEP(1, "8")
            MSTEP(2, "4")
            MSTEP(3, "0")
            __builtin_amdgcn_s_setprio(0);

            if (kc + 1 < NKC) {
                unsigned char* bp = (unsigned char*)&TIL[0][0] + (buf ^ 1) * BUF2;
                h8 hi, lo;
                cvt8(ga0, ga1, hi, lo);
                *(h8*)(bp + offA) = hi;  *(h8*)(bp + PLANE + offA) = lo;
                cvt8(gb00, gb01, hi, lo);
                *(h8*)(bp + 2 * PLANE + offB0) = hi;  *(h8*)(bp + 2 * PLANE + BPLANE + offB0) = lo;
                cvt8(gb10, gb11, hi, lo);
                *(h8*)(bp + 2 * PLANE + offB1) = hi;  *(h8*)(bp + 2 * PLANE + BPLANE + offB1) = lo;
                __syncthreads();
            }
        }

        #pragma unroll
        for (int n = 0; n < 4; ++n) {
            float m = acc[0][n][0];
            #pragma unroll
            for (int mm = 0; mm < 4; ++mm)
                #pragma unroll
                for (int r = 0; r < 4; ++r)
                    m = fmaxf(m, acc[mm][n][r]);
            m = fmaxf(m, __shfl_xor(m, 16));
            m = fmaxf(m, __shfl_xor(m, 32));
            if (lane < 16) redM[wi][wj * 64 + n * 16 + lr] = m;
        }
        __syncthreads();
        float mnew[4];
        #pragma unroll
        for (int n = 0; n < 4; ++n) {
            const int col = wj * 64 + n * 16 + lr;
            mnew[n] = fmaxf(Mrun[n], fmaxf(redM[0][col], redM[1][col]));
        }

        float z[4] = {0, 0, 0, 0}, y[4][3] = {{0,0,0},{0,0,0},{0,0,0},{0,0,0}};
        #pragma unroll
        for (int mm = 0; mm < 4; ++mm)
            #pragma unroll
            for (int r = 0; r < 4; ++r) {
                const int iL = wi * 64 + mm * 16 + lg * 4 + r;
                const float t0 = tgts[0][iL], t1 = tgts[1][iL], t2 = tgts[2][iL];
                #pragma unroll
                for (int n = 0; n < 4; ++n) {
                    const float e = __expf(acc[mm][n][r] - mnew[n]);
                    z[n] += e;
                    y[n][0] = fmaf(e, t0, y[n][0]);
                    y[n][1] = fmaf(e, t1, y[n][1]);
                    y[n][2] = fmaf(e, t2, y[n][2]);
                }
            }
        #pragma unroll
        for (int n = 0; n < 4; ++n) {
            #pragma unroll
            for (int off = 16; off <= 32; off <<= 1) {
                z[n]    += __shfl_xor(z[n], off);
                y[n][0] += __shfl_xor(y[n][0], off);
                y[n][1] += __shfl_xor(y[n][1], off);
                y[n][2] += __shfl_xor(y[n][2], off);
            }
            if (lane < 16)
                redS[wi][wj * 64 + n * 16 + lr] = make_float4(z[n], y[n][0], y[n][1], y[n][2]);
        }
        __syncthreads();
        #pragma unroll
        for (int n = 0; n < 4; ++n) {
            const int col = wj * 64 + n * 16 + lr;
            const float4 s0 = redS[0][col], s1 = redS[1][col];
            const float sc = __expf(Mrun[n] - mnew[n]);
            Zrun[n]    = Zrun[n]    * sc + s0.x + s1.x;
            Yrun[n][0] = Yrun[n][0] * sc + s0.y + s1.y;
            Yrun[n][1] = Yrun[n][1] * sc + s0.z + s1.z;
            Yrun[n][2] = Yrun[n][2] * sc + s0.w + s1.w;
            Mrun[n] = mnew[n];
        }
        __syncthreads();
    }

    if (wi == 0 && lane < 16) {
        #pragma unroll
        for (int n = 0; n < 4; ++n) {
            const int j   = j0 + wj * 64 + n * 16 + lr;
            const int idx = (b * 2 + ih) * NPT + j;
            stw[0 * (NB * 2 * NPT) + idx] = Mrun[n];
            stw[1 * (NB * 2 * NPT) + idx] = Zrun[n];
            stw[2 * (NB * 2 * NPT) + idx] = Yrun[n][0];
            stw[3 * (NB * 2 * NPT) + idx] = Yrun[n][1];
            stw[4 * (NB * 2 * NPT) + idx] = Yrun[n][2];
        }
    }
#undef RD_B
#undef RD_A
#undef BBLD
#undef MM3
#undef MSTEP
}

// ---------------------------------------------------------------------------
// Kernel B: per-batch 3x3 covariance -> SVD (Jacobi on S^T S) -> R, t
// ---------------------------------------------------------------------------
__device__ inline void jrot(float A[3][3], float V[3][3], int p, int q)
{
    const float apq = A[p][q];
    if (fabsf(apq) < 1e-28f) return;
    const float tau = (A[q][q] - A[p][p]) / (2.0f * apq);
    const float t   = (tau >= 0.0f ? 1.0f : -1.0f) / (fabsf(tau) + sqrtf(1.0f + tau * tau));
    const float c   = rsqrtf(1.0f + t * t);
    const float s   = t * c;
    const float app = A[p][p], aqq = A[q][q];
    A[p][p] = app - t * apq;
    A[q][q] = aqq + t * apq;
    A[p][q] = 0.0f; A[q][p] = 0.0f;
    const int r = 3 - p - q;
    const float arp = A[r][p], arq = A[r][q];
    A[r][p] = c * arp - s * arq; A[p][r] = A[r][p];
    A[r][q] = s * arp + c * arq; A[q][r] = A[r][q];
    #pragma unroll
    for (int rr = 0; rr < 3; ++rr) {
        const float vrp = V[rr][p], vrq = V[rr][q];
        V[rr][p] = c * vrp - s * vrq;
        V[rr][q] = s * vrp + c * vrq;
    }
}

__global__ void svd_finalize_kernel(const float* __restrict__ partials,
                                    float* __restrict__ out)
{
    const int b = threadIdx.x;
    if (b >= NB) return;

    float srcS[3] = {0, 0, 0}, predS[3] = {0, 0, 0}, SP[9] = {0, 0, 0, 0, 0, 0, 0, 0, 0};
    for (int p = 0; p < NJT; ++p) {
        const float* vv = partials + (((size_t)b << 4) + p) * 16;
        srcS[0] += vv[0]; srcS[1] += vv[1]; srcS[2] += vv[2];
        predS[0] += vv[3]; predS[1] += vv[4]; predS[2] += vv[5];
        #pragma unroll
        for (int q = 0; q < 9; ++q) SP[q] += vv[6 + q];
    }

    const float invN = 1.0f / (float)NPT;
    float ms[3], mt[3];
    #pragma unroll
    for (int c = 0; c < 3; ++c) { ms[c] = srcS[c] * invN; mt[c] = predS[c] * invN; }

    float S[3][3];
    #pragma unroll
    for (int c = 0; c < 3; ++c)
        #pragma unroll
        for (int d = 0; d < 3; ++d)
            S[c][d] = SP[c * 3 + d] - srcS[c] * predS[d] * invN;

    float A[3][3];
    #pragma unroll
    for (int i = 0; i < 3; ++i)
        #pragma unroll
        for (int j = 0; j < 3; ++j)
            A[i][j] = S[0][i] * S[0][j] + S[1][i] * S[1][j] + S[2][i] * S[2][j];

    float V[3][3] = {{1, 0, 0}, {0, 1, 0}, {0, 0, 1}};
    for (int sweep = 0; sweep < 12; ++sweep) {
        jrot(A, V, 0, 1);
        jrot(A, V, 0, 2);
        jrot(A, V, 1, 2);
    }

    float lam[3] = {A[0][0], A[1][1], A[2][2]};
    for (int i = 0; i < 2; ++i) {
        int mx = i;
        for (int j = i + 1; j < 3; ++j) if (lam[j] > lam[mx]) mx = j;
        if (mx != i) {
            const float tl = lam[i]; lam[i] = lam[mx]; lam[mx] = tl;
            #pragma unroll
            for (int r = 0; r < 3; ++r) {
                const float tv = V[r][i]; V[r][i] = V[r][mx]; V[r][mx] = tv;
            }
        }
    }

    float w0[3], w1[3], u1[3], u2[3], u3[3];
    #pragma unroll
    for (int r = 0; r < 3; ++r) {
        w0[r] = S[r][0] * V[0][0] + S[r][1] * V[1][0] + S[r][2] * V[2][0];
        w1[r] = S[r][0] * V[0][1] + S[r][1] * V[1][1] + S[r][2] * V[2][1];
    }
    const float n1 = sqrtf(w0[0] * w0[0] + w0[1] * w0[1] + w0[2] * w0[2]) + 1e-30f;
    #pragma unroll
    for (int r = 0; r < 3; ++r) u1[r] = w0[r] / n1;
    const float d01 = u1[0] * w1[0] + u1[1] * w1[1] + u1[2] * w1[2];
    #pragma unroll
    for (int r = 0; r < 3; ++r) u2[r] = w1[r] - d01 * u1[r];
    const float n2 = sqrtf(u2[0] * u2[0] + u2[1] * u2[1] + u2[2] * u2[2]) + 1e-30f;
    #pragma unroll
    for (int r = 0; r < 3; ++r) u2[r] /= n2;
    u3[0] = u1[1] * u2[2] - u1[2] * u2[1];
    u3[1] = u1[2] * u2[0] - u1[0] * u2[2];
    u3[2] = u1[0] * u2[1] - u1[1] * u2[0];

    const float detV =
        V[0][0] * (V[1][1] * V[2][2] - V[1][2] * V[2][1]) -
        V[0][1] * (V[1][0] * V[2][2] - V[1][2] * V[2][0]) +
        V[0][2] * (V[1][0] * V[2][1] - V[1][1] * V[2][0]);

    float R[3][3];
    #pragma unroll
    for (int r = 0; r < 3; ++r)
        #pragma unroll
        for (int c = 0; c < 3; ++c)
            R[r][c] = V[r][0] * u1[c] + V[r][1] * u2[c] + detV * V[r][2] * u3[c];

    #pragma unroll
    for (int r = 0; r < 3; ++r)
        #pragma unroll
        for (int c = 0; c < 3; ++c)
            out[b * 9 + r * 3 + c] = R[r][c];

    #pragma unroll
    for (int r = 0; r < 3; ++r) {
        const float tr = mt[r] - (R[r][0] * ms[0] + R[r][1] * ms[1] + R[r][2] * ms[2]);
        out[NB * 9 + b * 3 + r] = tr;
    }
}

extern "C" void kernel_launch(void* const* d_in, const int* in_sizes, int n_in,
                              void* d_out, int out_size, void* d_ws, size_t ws_size,
                              hipStream_t stream)
{
    const float* source  = (const float*)d_in[0];
    const float* target  = (const float*)d_in[1];
    const float* fsource = (const float*)d_in[2];
    const float* ftarget = (const float*)d_in[3];
    float* out = (float*)d_out;

    const size_t PART_FLOATS = (size_t)NB * 16 * 16;
    const size_t ST4_FLOATS  = (size_t)5 * NB * NIQ * NPT;
    const size_t ST2_FLOATS  = (size_t)5 * NB * 2 * NPT;
    const size_t NEED_BIG    = 2 * TPB1 + (ST4_FLOATS + PART_FLOATS) * 4;

    if (ws_size >= NEED_BIG) {
        _Float16* tiled = (_Float16*)d_ws;
        float* stw      = (float*)((char*)d_ws + 2 * TPB1);
        float* partials = stw + ST4_FLOATS;
        prepass_kernel<<<dim3(NB, NKC, 16), 256, 0, stream>>>(fsource, ftarget, tiled);
        attn_state_tiled<<<dim3(NB, 16, NIQ), 256, 0, stream>>>(target, tiled, stw);
        combine4_kernel<<<dim3(NB, 16), 128, 0, stream>>>(source, stw, partials);
        svd_finalize_kernel<<<1, 64, 0, stream>>>(partials, out);
    } else {
        float* stw      = (float*)d_ws;
        float* partials = stw + ST2_FLOATS;
        attn_state_kernel<<<dim3(NB, 8, 2), NTHR, 0, stream>>>(target, fsource, ftarget, stw);
        combine_kernel<<<dim3(NB, 16), 128, 0, stream>>>(source, stw, partials);
        svd_finalize_kernel<<<1, 64, 0, stream>>>(partials, out);
    }
}

// Round 14
// 144.174 us; speedup vs baseline: 1.0042x; 1.0042x over previous
//
#include <hip/hip_runtime.h>
#include <math.h>
#include <stdint.h>

#define NB   16
#define NPT  2048
#define NF   512
#define BI   128
#define BJ   128
#define KB   32
#define NTHR 512
#define NJT  (NPT / BJ)   // 16
#define NIT  (NPT / BI)   // 16
#define NKC  (NF / KB)    // 16
#define NIQ  4            // i-quarters (512 rows each), main path

// ---- tiled fp16 HI-ONLY global layout (main path) ----
// per tensor: [b][kc][cg(128)] x 1024B; cg block = [hi kh0 | hi kh1] 512B
// windows; window = [kg(4)][j(4)][c(16)] fp16 (tr-read order, verified r3).
#define CGB1     1024
#define KCSLAB1  (128 * CGB1)                      // 128 KB per (b,kc)
#define TPB1     ((size_t)NB * NKC * KCSLAB1)      // 32 MB per tensor

// ---- fallback (round-4) padded LDS geometry (3-term hi/lo) ----
#define CGS    1056
#define PLANE  8448
#define PLANE_H 4224
#define BPLANE 16896
#define BUF2   50688

typedef _Float16 h4 __attribute__((ext_vector_type(4)));
typedef _Float16 h8 __attribute__((ext_vector_type(8)));
typedef float    f32x4 __attribute__((ext_vector_type(4)));

// ds_read_b64_tr_b16, NATURAL addressing (base + lane*8): 64 lanes cover a
// 512B [16k][16col] window; lane l gets col (l&15), k = 4*(l>>4)+j. [m156/m162]
#define TRR(dst, a) asm volatile("ds_read_b64_tr_b16 %0, %1" : "=v"(dst) : "v"(a))

#define MF(A, B, C) __builtin_amdgcn_mfma_f32_16x16x32_f16(A, B, C, 0, 0, 0)

__device__ __forceinline__ void gld16(const void* g, void* l) {
    __builtin_amdgcn_global_load_lds(
        (const __attribute__((address_space(1))) unsigned int*)g,
        (__attribute__((address_space(3))) unsigned int*)l, 16, 0, 0);
}

__device__ __forceinline__ h8 cat(h4 a, h4 b) {
    return __builtin_shufflevector(a, b, 0, 1, 2, 3, 4, 5, 6, 7);
}

__device__ __forceinline__ void cvt8(const float4 a, const float4 b, h8& hi, h8& lo) {
    hi[0] = (_Float16)a.x; hi[1] = (_Float16)a.y;
    hi[2] = (_Float16)a.z; hi[3] = (_Float16)a.w;
    hi[4] = (_Float16)b.x; hi[5] = (_Float16)b.y;
    hi[6] = (_Float16)b.z; hi[7] = (_Float16)b.w;
    lo[0] = (_Float16)(a.x - (float)hi[0]);
    lo[1] = (_Float16)(a.y - (float)hi[1]);
    lo[2] = (_Float16)(a.z - (float)hi[2]);
    lo[3] = (_Float16)(a.w - (float)hi[3]);
    lo[4] = (_Float16)(b.x - (float)hi[4]);
    lo[5] = (_Float16)(b.y - (float)hi[5]);
    lo[6] = (_Float16)(b.z - (float)hi[6]);
    lo[7] = (_Float16)(b.w - (float)hi[7]);
}

__device__ __forceinline__ h8 cvt8h(const float4 a, const float4 b) {
    h8 hi;
    hi[0] = (_Float16)a.x; hi[1] = (_Float16)a.y;
    hi[2] = (_Float16)a.z; hi[3] = (_Float16)a.w;
    hi[4] = (_Float16)b.x; hi[5] = (_Float16)b.y;
    hi[6] = (_Float16)b.z; hi[7] = (_Float16)b.w;
    return hi;
}

__device__ __forceinline__ int hoffB(int f, int n8) {
    return (n8 >> 1) * CGS + (f >> 4) * 512 + ((f >> 2) & 3) * 128
         + (f & 3) * 32 + (n8 & 1) * 16;
}

// ---------------------------------------------------------------------------
// Prepass: fp32 -> tiled fp16 HI-ONLY (tr-window byte order). Unchanged r11.
// ---------------------------------------------------------------------------
__global__ __launch_bounds__(256)
void prepass_kernel(const float* __restrict__ fsource,
                    const float* __restrict__ ftarget,
                    _Float16* __restrict__ tiled)
{
    const int b  = blockIdx.x;
    const int kc = blockIdx.y;
    const int z  = blockIdx.z;            // tensor(2) x cgrp(8)
    const int tensor = z >> 3;
    const int cgrp   = z & 7;
    const float* src = (tensor == 0 ? ftarget : fsource)
                     + (size_t)b * NF * NPT + (size_t)kc * KB * NPT + cgrp * 256;
    char* dst = (char*)tiled + (size_t)tensor * TPB1
              + ((size_t)(b * NKC + kc) * 128 + cgrp * 16) * CGB1;

    __shared__ _Float16 sm[8448];         // 16 cg x 1056B (pad +32B)
    const int t   = threadIdx.x;
    const int kk8 = t >> 5;               // 0..7
    const int c8  = (t & 31) * 8;         // 0..248
    const int cg  = c8 >> 4;
    const int cl  = c8 & 15;              // 0 or 8

    #pragma unroll
    for (int rep = 0; rep < 4; ++rep) {
        const int k = rep * 8 + kk8;      // 0..31
        const float4 v0 = *(const float4*)(src + (size_t)k * NPT + c8);
        const float4 v1 = *(const float4*)(src + (size_t)k * NPT + c8 + 4);
        const h8 hi = cvt8h(v0, v1);
        const int kh = k >> 4, kr = k & 15, kg = kr >> 2, j = kr & 3;
        *(h8*)((char*)sm + cg * 1056 + kh * 512 + kg * 128 + j * 32 + cl * 2) = hi;
    }
    __syncthreads();
    #pragma unroll
    for (int q = 0; q < 4; ++q) {
        const int off = q * 4096 + t * 16;         // 16 KB, lanes contiguous
        const int ocg = off >> 10, rem = off & 1023;
        *(float4*)(dst + off) = *(const float4*)((char*)sm + ocg * 1056 + rem);
    }
}

// ---------------------------------------------------------------------------
// Main GEMM kernel (round-14): r13 BK=64 schedule with HOISTED addressing —
// per-thread global staging pointers advanced by a constant stride per step,
// LDS dests and tr-read bases precomputed once. Schedule byte-identical.
// LDS 75 KB -> 2 blocks/CU. Grid (16 b, 16 jt, 4 iq) = 1024 blocks.
// ---------------------------------------------------------------------------
__global__ __launch_bounds__(256, 2)
void attn_state_tiled(const float* __restrict__ target,
                      const _Float16* __restrict__ tiled,
                      float* __restrict__ stw)    // [5][16*4*2048]
{
    const int b    = blockIdx.x;
    const int jt   = blockIdx.y;          // 0..15
    const int iq   = blockIdx.z;          // 0..3
    const int j0   = jt * BJ;
    const int tid  = threadIdx.x;
    const int lane = tid & 63;
    const int wave = tid >> 6;            // 0..3
    const int wi   = wave >> 1;           // 0..1: rows [wi*64, +64)
    const int wj   = wave & 1;            // 0..1: cols [wj*64, +64)
    const int lg   = lane >> 4;
    const int lr   = lane & 15;

    // per buf (32 KB): A_even @0, A_odd @8192, B_even @16384, B_odd @24576
    __shared__ __align__(16) char TIL[2][32768];
    __shared__ float  tgtsAll[3][512];            // all 512 i-rows of this block
    __shared__ float  redM[2][BJ];
    __shared__ float4 redS[2][BJ];

    const uint32_t tilesBase = (uint32_t)(uintptr_t)&TIL[0][0];
    const uint32_t trLane    = (uint32_t)(lane * 8);

    // hoisted per-thread constants
    const uint32_t aB0 = tilesBase + (uint32_t)(wi * 4) * CGB1 + trLane;
    const uint32_t bB0 = tilesBase + 16384u + (uint32_t)(wj * 4) * CGB1 + trLane;
    char* const lbw0 = &TIL[0][0] + wave * 1024;
    char* const lbw1 = &TIL[1][0] + wave * 1024;

    const char* Atile = (const char*)tiled;          // ftarget tiled (hi)
    const char* Btile = (const char*)tiled + TPB1;   // fsource tiled (hi)
    const size_t thrBase = (size_t)(b * NKC) * KCSLAB1 + lane * 16 + wave * 1024;
    const size_t boffB   = (size_t)(j0 >> 4) * CGB1;

    // ---- once: preload target coords for the block's 512 i-rows ----
    {
        const float* tg = target + ((size_t)b * NPT + iq * 512) * 3;
        #pragma unroll
        for (int k = 0; k < 6; ++k) {
            const int p = tid + k * 256;   // 0..1535 = row*3 + c
            tgtsAll[p % 3][p / 3] = tg[p];
        }
    }
    __syncthreads();

    float Mrun[4], Zrun[4], Yrun[4][3];
    #pragma unroll
    for (int n = 0; n < 4; ++n) {
        Mrun[n] = -3.0e38f; Zrun[n] = 0.0f;
        Yrun[n][0] = 0.0f; Yrun[n][1] = 0.0f; Yrun[n][2] = 0.0f;
    }

#define STAGE2P(pa, pb, lb) { \
    gld16((pa),                  (lb)); \
    gld16((pa) + 4096,           (lb) + 4096); \
    gld16((pa) + KCSLAB1,        (lb) + 8192); \
    gld16((pa) + KCSLAB1 + 4096, (lb) + 8192 + 4096); \
    gld16((pb),                  (lb) + 16384); \
    gld16((pb) + 4096,           (lb) + 16384 + 4096); \
    gld16((pb) + KCSLAB1,        (lb) + 24576); \
    gld16((pb) + KCSLAB1 + 4096, (lb) + 24576 + 4096); }

#define RD_A1(m) TRR(ta[m][0], aB + (m) * CGB1); \
                 TRR(ta[m][1], aB + (m) * CGB1 + 512);
#define RD_B1(n) TRR(tb[n][0], bB + (n) * CGB1); \
                 TRR(tb[n][1], bB + (n) * CGB1 + 512);
#define WAITK(N) asm volatile("s_waitcnt lgkmcnt(" #N ")" ::: "memory"); \
                 __builtin_amdgcn_sched_barrier(0);
#define MROW1(M) \
    { const h8 Ah = cat(ta[M][0], ta[M][1]); \
      acc[M][0] = MF(Ah, Bh[0], acc[M][0]); \
      acc[M][1] = MF(Ah, Bh[1], acc[M][1]); \
      acc[M][2] = MF(Ah, Bh[2], acc[M][2]); \
      acc[M][3] = MF(Ah, Bh[3], acc[M][3]); }

// One K=32 half: 16 tr-reads + 16 MFMAs with the proven 6/4/2/0 ladder.
#define KHALF(aBv, bBv) { \
    const uint32_t aB = (aBv); \
    const uint32_t bB = (bBv); \
    h4 ta[4][2], tb[4][2]; \
    h8 Bh[4]; \
    RD_A1(0) RD_B1(0) RD_B1(1) RD_B1(2) RD_B1(3) \
    RD_A1(1) RD_A1(2) RD_A1(3) \
    WAITK(6) \
    Bh[0] = cat(tb[0][0], tb[0][1]); \
    Bh[1] = cat(tb[1][0], tb[1][1]); \
    Bh[2] = cat(tb[2][0], tb[2][1]); \
    Bh[3] = cat(tb[3][0], tb[3][1]); \
    MROW1(0) \
    WAITK(4) MROW1(1) \
    WAITK(2) MROW1(2) \
    WAITK(0) MROW1(3) }

    for (int it = 0; it < 4; ++it) {
        const int i0 = iq * 512 + it * BI;

        // staging pointers for this i-tile; advance by 2*KCSLAB1 per step
        const char* pAs = Atile + thrBase + (size_t)(i0 >> 4) * CGB1;
        const char* pBs = Btile + thrBase + boffB;

        // ---- prologue: stage step 0 into buf0 ----
        STAGE2P(pAs, pBs, lbw0)
        pAs += 2 * (size_t)KCSLAB1;  pBs += 2 * (size_t)KCSLAB1;
        asm volatile("s_waitcnt vmcnt(0)" ::: "memory");
        __builtin_amdgcn_sched_barrier(0);
        __syncthreads();

        f32x4 acc[4][4];
        #pragma unroll
        for (int m = 0; m < 4; ++m)
            #pragma unroll
            for (int n = 0; n < 4; ++n)
                acc[m][n] = (f32x4){0.0f, 0.0f, 0.0f, 0.0f};

        for (int kc2 = 0; kc2 < 8; ++kc2) {
            // prefetch next BK=64 step into the other buffer
            if (kc2 + 1 < 8) {
                STAGE2P(pAs, pBs, (kc2 & 1) ? lbw0 : lbw1)
                pAs += 2 * (size_t)KCSLAB1;  pBs += 2 * (size_t)KCSLAB1;
            }

            const uint32_t bofs = (uint32_t)((kc2 & 1) << 15);   // 0 or 32768
            __builtin_amdgcn_s_setprio(1);
            KHALF(aB0 + bofs, bB0 + bofs)
            KHALF(aB0 + bofs + 8192u, bB0 + bofs + 8192u)
            __builtin_amdgcn_s_setprio(0);

            asm volatile("s_waitcnt vmcnt(0)" ::: "memory");
            __builtin_amdgcn_sched_barrier(0);
            __syncthreads();
        }

        // ---- online softmax update for this i-tile ----
        // D layout: col j = wj*64 + n*16 + lr, row i = wi*64 + m*16 + lg*4 + r
        #pragma unroll
        for (int n = 0; n < 4; ++n) {
            float m = acc[0][n][0];
            #pragma unroll
            for (int mm = 0; mm < 4; ++mm)
                #pragma unroll
                for (int r = 0; r < 4; ++r)
                    m = fmaxf(m, acc[mm][n][r]);
            m = fmaxf(m, __shfl_xor(m, 16));
            m = fmaxf(m, __shfl_xor(m, 32));
            if (lane < 16) redM[wi][wj * 64 + n * 16 + lr] = m;
        }
        __syncthreads();
        float mnew[4];
        #pragma unroll
        for (int n = 0; n < 4; ++n) {
            const int col = wj * 64 + n * 16 + lr;
            mnew[n] = fmaxf(Mrun[n], fmaxf(redM[0][col], redM[1][col]));
        }

        float z[4] = {0, 0, 0, 0}, y[4][3] = {{0,0,0},{0,0,0},{0,0,0},{0,0,0}};
        #pragma unroll
        for (int mm = 0; mm < 4; ++mm)
            #pragma unroll
            for (int r = 0; r < 4; ++r) {
                const int iL = it * BI + wi * 64 + mm * 16 + lg * 4 + r;
                const float t0 = tgtsAll[0][iL], t1 = tgtsAll[1][iL], t2 = tgtsAll[2][iL];
                #pragma unroll
                for (int n = 0; n < 4; ++n) {
                    const float e = __expf(acc[mm][n][r] - mnew[n]);
                    z[n] += e;
                    y[n][0] = fmaf(e, t0, y[n][0]);
                    y[n][1] = fmaf(e, t1, y[n][1]);
                    y[n][2] = fmaf(e, t2, y[n][2]);
                }
            }
        #pragma unroll
        for (int n = 0; n < 4; ++n) {
            #pragma unroll
            for (int off = 16; off <= 32; off <<= 1) {
                z[n]    += __shfl_xor(z[n], off);
                y[n][0] += __shfl_xor(y[n][0], off);
                y[n][1] += __shfl_xor(y[n][1], off);
                y[n][2] += __shfl_xor(y[n][2], off);
            }
            if (lane < 16)
                redS[wi][wj * 64 + n * 16 + lr] = make_float4(z[n], y[n][0], y[n][1], y[n][2]);
        }
        __syncthreads();
        #pragma unroll
        for (int n = 0; n < 4; ++n) {
            const int col = wj * 64 + n * 16 + lr;
            const float4 s0 = redS[0][col], s1 = redS[1][col];
            const float sc = __expf(Mrun[n] - mnew[n]);
            Zrun[n]    = Zrun[n]    * sc + s0.x + s1.x;
            Yrun[n][0] = Yrun[n][0] * sc + s0.y + s1.y;
            Yrun[n][1] = Yrun[n][1] * sc + s0.z + s1.z;
            Yrun[n][2] = Yrun[n][2] * sc + s0.w + s1.w;
            Mrun[n] = mnew[n];
        }
        __syncthreads();   // protect redM/redS/TIL before next it's staging
    }

    // ---- write per-column state ----
    if (wi == 0 && lane < 16) {
        const int SP4 = NB * NIQ * NPT;
        #pragma unroll
        for (int n = 0; n < 4; ++n) {
            const int j   = j0 + wj * 64 + n * 16 + lr;
            const int idx = (b * NIQ + iq) * NPT + j;
            stw[idx]           = Mrun[n];
            stw[SP4 + idx]     = Zrun[n];
            stw[2 * SP4 + idx] = Yrun[n][0];
            stw[3 * SP4 + idx] = Yrun[n][1];
            stw[4 * SP4 + idx] = Yrun[n][2];
        }
    }
#undef STAGE2P
#undef RD_A1
#undef RD_B1
#undef WAITK
#undef MROW1
#undef KHALF
}

// ---------------------------------------------------------------------------
// Combine (main path): merge the 4 i-quarter softmax states per column,
// compute pred, per-(b, 128-j-chunk) partial sums (15 values).
// ---------------------------------------------------------------------------
__global__ void combine4_kernel(const float* __restrict__ source,
                                const float* __restrict__ stw,
                                float* __restrict__ partials)
{
    const int b   = blockIdx.x;
    const int jc  = blockIdx.y;     // 0..15
    const int tid = threadIdx.x;    // 128
    const int lane = tid & 63, wv = tid >> 6;
    const int j = jc * BJ + tid;
    const int SP = NB * NIQ * NPT;

    __shared__ float fin2[2][15];

    float m[NIQ], zz[NIQ], yy0[NIQ], yy1[NIQ], yy2[NIQ];
    #pragma unroll
    for (int q = 0; q < NIQ; ++q) {
        const int idx = (b * NIQ + q) * NPT + j;
        m[q]   = stw[idx];
        zz[q]  = stw[SP + idx];
        yy0[q] = stw[2 * SP + idx];
        yy1[q] = stw[3 * SP + idx];
        yy2[q] = stw[4 * SP + idx];
    }
    float ms = m[0];
    #pragma unroll
    for (int q = 1; q < NIQ; ++q) ms = fmaxf(ms, m[q]);
    float Z = 0, Y0 = 0, Y1 = 0, Y2 = 0;
    #pragma unroll
    for (int q = 0; q < NIQ; ++q) {
        const float s = __expf(m[q] - ms);
        Z  += zz[q]  * s;
        Y0 += yy0[q] * s;
        Y1 += yy1[q] * s;
        Y2 += yy2[q] * s;
    }
    const float iz = 1.0f / Z;
    const float p0 = Y0 * iz, p1 = Y1 * iz, p2 = Y2 * iz;

    const float* sp = source + ((size_t)b * NPT + j) * 3;
    const float s0 = sp[0], s1 = sp[1], s2 = sp[2];

    float v[15];
    v[0] = s0; v[1] = s1; v[2] = s2;
    v[3] = p0; v[4] = p1; v[5] = p2;
    v[6]  = s0 * p0; v[7]  = s0 * p1; v[8]  = s0 * p2;
    v[9]  = s1 * p0; v[10] = s1 * p1; v[11] = s1 * p2;
    v[12] = s2 * p0; v[13] = s2 * p1; v[14] = s2 * p2;

    #pragma unroll
    for (int q = 0; q < 15; ++q)
        #pragma unroll
        for (int off = 32; off > 0; off >>= 1)
            v[q] += __shfl_down(v[q], off);
    if (lane == 0) {
        #pragma unroll
        for (int q = 0; q < 15; ++q) fin2[wv][q] = v[q];
    }
    __syncthreads();
    if (tid == 0) {
        float* o = partials + (((size_t)b << 4) + jc) * 16;
        #pragma unroll
        for (int q = 0; q < 15; ++q) o[q] = fin2[0][q] + fin2[1][q];
    }
}

// ---------------------------------------------------------------------------
// Combine (fallback): merge two i-half states (round-7 code).
// ---------------------------------------------------------------------------
__global__ void combine_kernel(const float* __restrict__ source,
                               const float* __restrict__ stw,
                               float* __restrict__ partials)
{
    const int b   = blockIdx.x;
    const int jc  = blockIdx.y;
    const int tid = threadIdx.x;    // 128
    const int lane = tid & 63, wv = tid >> 6;
    const int j = jc * BJ + tid;
    const int SP = NB * 2 * NPT;
    const int i0 = (b * 2 + 0) * NPT + j;
    const int i1 = (b * 2 + 1) * NPT + j;

    __shared__ float fin2[2][15];

    const float ma = stw[i0],      mb = stw[i1];
    const float za = stw[SP + i0], zb = stw[SP + i1];
    const float ms = fmaxf(ma, mb);
    const float sa = __expf(ma - ms), sb = __expf(mb - ms);
    const float zt = za * sa + zb * sb;
    const float iz = 1.0f / zt;
    const float p0 = (stw[2 * SP + i0] * sa + stw[2 * SP + i1] * sb) * iz;
    const float p1 = (stw[3 * SP + i0] * sa + stw[3 * SP + i1] * sb) * iz;
    const float p2 = (stw[4 * SP + i0] * sa + stw[4 * SP + i1] * sb) * iz;

    const float* sp = source + ((size_t)b * NPT + j) * 3;
    const float s0 = sp[0], s1 = sp[1], s2 = sp[2];

    float v[15];
    v[0] = s0; v[1] = s1; v[2] = s2;
    v[3] = p0; v[4] = p1; v[5] = p2;
    v[6]  = s0 * p0; v[7]  = s0 * p1; v[8]  = s0 * p2;
    v[9]  = s1 * p0; v[10] = s1 * p1; v[11] = s1 * p2;
    v[12] = s2 * p0; v[13] = s2 * p1; v[14] = s2 * p2;

    #pragma unroll
    for (int q = 0; q < 15; ++q)
        #pragma unroll
        for (int off = 32; off > 0; off >>= 1)
            v[q] += __shfl_down(v[q], off);
    if (lane == 0) {
        #pragma unroll
        for (int q = 0; q < 15; ++q) fin2[wv][q] = v[q];
    }
    __syncthreads();
    if (tid == 0) {
        float* o = partials + (((size_t)b << 4) + jc) * 16;
        #pragma unroll
        for (int q = 0; q < 15; ++q) o[q] = fin2[0][q] + fin2[1][q];
    }
}

// ---------------------------------------------------------------------------
// Fallback (round-4 proven, 3-term hi/lo): in-loop cvt staging.
// ---------------------------------------------------------------------------
__global__ __launch_bounds__(NTHR, 2)
void attn_state_kernel(const float* __restrict__ target,
                       const float* __restrict__ fsource,
                       const float* __restrict__ ftarget,
                       float* __restrict__ stw)
{
    const int b    = blockIdx.x;
    const int jt   = blockIdx.y;
    const int ih   = blockIdx.z;
    const int j0   = jt * 256;
    const int tid  = threadIdx.x;
    const int lane = tid & 63;
    const int wave = tid >> 6;
    const int wi   = wave >> 2;
    const int wj   = wave & 3;
    const int lg   = lane >> 4;
    const int lr   = lane & 15;

    __shared__ __align__(16) unsigned char TIL[2][BUF2];
    __shared__ float  tgts[3][BI];
    __shared__ float  redM[2][256];
    __shared__ float4 redS[2][256];

    const uint32_t tilesBase = (uint32_t)(uintptr_t)&TIL[0][0];
    const uint32_t trLane    = (uint32_t)(lane * 8);
    const size_t   fbase     = (size_t)b * NF * NPT;

    const int fA  = tid >> 4,  n8A  = tid & 15;
    const int fB0 = tid >> 5,  n8B  = tid & 31;
    const int fB1 = (tid + 512) >> 5;
    const int offA  = hoffB(fA, n8A);
    const int offB0 = hoffB(fB0, n8B);
    const int offB1 = hoffB(fB1, n8B);

    float Mrun[4], Zrun[4], Yrun[4][3];
    #pragma unroll
    for (int n = 0; n < 4; ++n) {
        Mrun[n] = -3.0e38f; Zrun[n] = 0.0f;
        Yrun[n][0] = 0.0f; Yrun[n][1] = 0.0f; Yrun[n][2] = 0.0f;
    }

#define RD_B(n) TRR(tb[n][0][0], bB + (n) * CGS); \
                TRR(tb[n][0][1], bB + (n) * CGS + 512); \
                TRR(tb[n][1][0], bB + (n) * CGS + BPLANE); \
                TRR(tb[n][1][1], bB + (n) * CGS + BPLANE + 512);
#define RD_A(m) TRR(ta[m][0][0], aB + (m) * CGS); \
                TRR(ta[m][0][1], aB + (m) * CGS + 512); \
                TRR(ta[m][1][0], aB + (m) * CGS + PLANE); \
                TRR(ta[m][1][1], aB + (m) * CGS + PLANE + 512);
#define BBLD(n) Bh[n] = cat(tb[n][0][0], tb[n][0][1]); \
                Bl[n] = cat(tb[n][1][0], tb[n][1][1]);
#define MM3(M, N) \
    acc[M][N] = MF(Ah, Bh[N], acc[M][N]); \
    acc[M][N] = MF(Ah, Bl[N], acc[M][N]); \
    acc[M][N] = MF(Al, Bh[N], acc[M][N]);
#define MSTEP(M, WAITSTR) \
    asm volatile("s_waitcnt lgkmcnt(" WAITSTR ")" ::: "memory"); \
    __builtin_amdgcn_sched_barrier(0); \
    { const h8 Ah = cat(ta[M][0][0], ta[M][0][1]); \
      const h8 Al = cat(ta[M][1][0], ta[M][1][1]); \
      MM3(M, 0) MM3(M, 1) MM3(M, 2) MM3(M, 3) }

    for (int it = 0; it < 8; ++it) {
        const int i0 = ih * 1024 + it * BI;

        const float* pA  = ftarget + fbase + (size_t)fA  * NPT + i0 + n8A * 8;
        const float* pB0 = fsource + fbase + (size_t)fB0 * NPT + j0 + n8B * 8;
        const float* pB1 = fsource + fbase + (size_t)fB1 * NPT + j0 + n8B * 8;

        {
            float4 a0  = *(const float4*)(pA);
            float4 a1  = *(const float4*)(pA + 4);
            float4 b00 = *(const float4*)(pB0);
            float4 b01 = *(const float4*)(pB0 + 4);
            float4 b10 = *(const float4*)(pB1);
            float4 b11 = *(const float4*)(pB1 + 4);
            if (tid < BI) {
                const float* tp = target + ((size_t)b * NPT + i0 + tid) * 3;
                tgts[0][tid] = tp[0]; tgts[1][tid] = tp[1]; tgts[2][tid] = tp[2];
            }
            unsigned char* bp = (unsigned char*)&TIL[0][0];
            h8 hi, lo;
            cvt8(a0, a1, hi, lo);
            *(h8*)(bp + offA) = hi;  *(h8*)(bp + PLANE + offA) = lo;
            cvt8(b00, b01, hi, lo);
            *(h8*)(bp + 2 * PLANE + offB0) = hi;  *(h8*)(bp + 2 * PLANE + BPLANE + offB0) = lo;
            cvt8(b10, b11, hi, lo);
            *(h8*)(bp + 2 * PLANE + offB1) = hi;  *(h8*)(bp + 2 * PLANE + BPLANE + offB1) = lo;
        }
        __syncthreads();

        f32x4 acc[4][4];
        #pragma unroll
        for (int m = 0; m < 4; ++m)
            #pragma unroll
            for (int n = 0; n < 4; ++n)
                acc[m][n] = (f32x4){0.0f, 0.0f, 0.0f, 0.0f};

        for (int kc = 0; kc < NKC; ++kc) {
            const int buf = kc & 1;
            float4 ga0, ga1, gb00, gb01, gb10, gb11;
            if (kc + 1 < NKC) {
                const size_t ko = (size_t)(kc + 1) * KB * NPT;
                ga0  = *(const float4*)(pA + ko);
                ga1  = *(const float4*)(pA + ko + 4);
                gb00 = *(const float4*)(pB0 + ko);
                gb01 = *(const float4*)(pB0 + ko + 4);
                gb10 = *(const float4*)(pB1 + ko);
                gb11 = *(const float4*)(pB1 + ko + 4);
            }

            const uint32_t bb = tilesBase + (uint32_t)buf * BUF2;
            const uint32_t aB = bb + (uint32_t)(wi * 4) * CGS + trLane;
            const uint32_t bB = bb + 2u * PLANE + (uint32_t)(wj * 4) * CGS + trLane;
            h4 ta[4][2][2], tb[4][2][2];
            h8 Bh[4], Bl[4];

            __builtin_amdgcn_s_setprio(1);
            RD_B(0) RD_B(1) RD_B(2) RD_B(3)
            RD_A(0) RD_A(1) RD_A(2) RD_A(3)
            asm volatile("s_waitcnt lgkmcnt(12)" ::: "memory");
            __builtin_amdgcn_sched_barrier(0);
            BBLD(0) BBLD(1) BBLD(2) BBLD(3)
            {
                const h8 Ah = cat(ta[0][0][0], ta[0][0][1]);
                const h8 Al = cat(ta[0][1][0], ta[0][1][1]);
                MM3(0, 0) MM3(0, 1) MM3(0, 2) MM3(0, 3)
            }
            MSTEP(1, "8")
            MSTEP(2, "4")
            MSTEP(3, "0")
            __builtin_amdgcn_s_setprio(0);

            if (kc + 1 < NKC) {
                unsigned char* bp = (unsigned char*)&TIL[0][0] + (buf ^ 1) * BUF2;
                h8 hi, lo;
                cvt8(ga0, ga1, hi, lo);
                *(h8*)(bp + offA) = hi;  *(h8*)(bp + PLANE + offA) = lo;
                cvt8(gb00, gb01, hi, lo);
                *(h8*)(bp + 2 * PLANE + offB0) = hi;  *(h8*)(bp + 2 * PLANE + BPLANE + offB0) = lo;
                cvt8(gb10, gb11, hi, lo);
                *(h8*)(bp + 2 * PLANE + offB1) = hi;  *(h8*)(bp + 2 * PLANE + BPLANE + offB1) = lo;
                __syncthreads();
            }
        }

        #pragma unroll
        for (int n = 0; n < 4; ++n) {
            float m = acc[0][n][0];
            #pragma unroll
            for (int mm = 0; mm < 4; ++mm)
                #pragma unroll
                for (int r = 0; r < 4; ++r)
                    m = fmaxf(m, acc[mm][n][r]);
            m = fmaxf(m, __shfl_xor(m, 16));
            m = fmaxf(m, __shfl_xor(m, 32));
            if (lane < 16) redM[wi][wj * 64 + n * 16 + lr] = m;
        }
        __syncthreads();
        float mnew[4];
        #pragma unroll
        for (int n = 0; n < 4; ++n) {
            const int col = wj * 64 + n * 16 + lr;
            mnew[n] = fmaxf(Mrun[n], fmaxf(redM[0][col], redM[1][col]));
        }

        float z[4] = {0, 0, 0, 0}, y[4][3] = {{0,0,0},{0,0,0},{0,0,0},{0,0,0}};
        #pragma unroll
        for (int mm = 0; mm < 4; ++mm)
            #pragma unroll
            for (int r = 0; r < 4; ++r) {
                const int iL = wi * 64 + mm * 16 + lg * 4 + r;
                const float t0 = tgts[0][iL], t1 = tgts[1][iL], t2 = tgts[2][iL];
                #pragma unroll
                for (int n = 0; n < 4; ++n) {
                    const float e = __expf(acc[mm][n][r] - mnew[n]);
                    z[n] += e;
                    y[n][0] = fmaf(e, t0, y[n][0]);
                    y[n][1] = fmaf(e, t1, y[n][1]);
                    y[n][2] = fmaf(e, t2, y[n][2]);
                }
            }
        #pragma unroll
        for (int n = 0; n < 4; ++n) {
            #pragma unroll
            for (int off = 16; off <= 32; off <<= 1) {
                z[n]    += __shfl_xor(z[n], off);
                y[n][0] += __shfl_xor(y[n][0], off);
                y[n][1] += __shfl_xor(y[n][1], off);
                y[n][2] += __shfl_xor(y[n][2], off);
            }
            if (lane < 16)
                redS[wi][wj * 64 + n * 16 + lr] = make_float4(z[n], y[n][0], y[n][1], y[n][2]);
        }
        __syncthreads();
        #pragma unroll
        for (int n = 0; n < 4; ++n) {
            const int col = wj * 64 + n * 16 + lr;
            const float4 s0 = redS[0][col], s1 = redS[1][col];
            const float sc = __expf(Mrun[n] - mnew[n]);
            Zrun[n]    = Zrun[n]    * sc + s0.x + s1.x;
            Yrun[n][0] = Yrun[n][0] * sc + s0.y + s1.y;
            Yrun[n][1] = Yrun[n][1] * sc + s0.z + s1.z;
            Yrun[n][2] = Yrun[n][2] * sc + s0.w + s1.w;
            Mrun[n] = mnew[n];
        }
        __syncthreads();
    }

    if (wi == 0 && lane < 16) {
        #pragma unroll
        for (int n = 0; n < 4; ++n) {
            const int j   = j0 + wj * 64 + n * 16 + lr;
            const int idx = (b * 2 + ih) * NPT + j;
            stw[0 * (NB * 2 * NPT) + idx] = Mrun[n];
            stw[1 * (NB * 2 * NPT) + idx] = Zrun[n];
            stw[2 * (NB * 2 * NPT) + idx] = Yrun[n][0];
            stw[3 * (NB * 2 * NPT) + idx] = Yrun[n][1];
            stw[4 * (NB * 2 * NPT) + idx] = Yrun[n][2];
        }
    }
#undef RD_B
#undef RD_A
#undef BBLD
#undef MM3
#undef MSTEP
}

// ---------------------------------------------------------------------------
// Kernel B: per-batch 3x3 covariance -> SVD (Jacobi on S^T S) -> R, t
// ---------------------------------------------------------------------------
__device__ inline void jrot(float A[3][3], float V[3][3], int p, int q)
{
    const float apq = A[p][q];
    if (fabsf(apq) < 1e-28f) return;
    const float tau = (A[q][q] - A[p][p]) / (2.0f * apq);
    const float t   = (tau >= 0.0f ? 1.0f : -1.0f) / (fabsf(tau) + sqrtf(1.0f + tau * tau));
    const float c   = rsqrtf(1.0f + t * t);
    const float s   = t * c;
    const float app = A[p][p], aqq = A[q][q];
    A[p][p] = app - t * apq;
    A[q][q] = aqq + t * apq;
    A[p][q] = 0.0f; A[q][p] = 0.0f;
    const int r = 3 - p - q;
    const float arp = A[r][p], arq = A[r][q];
    A[r][p] = c * arp - s * arq; A[p][r] = A[r][p];
    A[r][q] = s * arp + c * arq; A[q][r] = A[r][q];
    #pragma unroll
    for (int rr = 0; rr < 3; ++rr) {
        const float vrp = V[rr][p], vrq = V[rr][q];
        V[rr][p] = c * vrp - s * vrq;
        V[rr][q] = s * vrp + c * vrq;
    }
}

__global__ void svd_finalize_kernel(const float* __restrict__ partials,
                                    float* __restrict__ out)
{
    const int b = threadIdx.x;
    if (b >= NB) return;

    float srcS[3] = {0, 0, 0}, predS[3] = {0, 0, 0}, SP[9] = {0, 0, 0, 0, 0, 0, 0, 0, 0};
    for (int p = 0; p < NJT; ++p) {
        const float* vv = partials + (((size_t)b << 4) + p) * 16;
        srcS[0] += vv[0]; srcS[1] += vv[1]; srcS[2] += vv[2];
        predS[0] += vv[3]; predS[1] += vv[4]; predS[2] += vv[5];
        #pragma unroll
        for (int q = 0; q < 9; ++q) SP[q] += vv[6 + q];
    }

    const float invN = 1.0f / (float)NPT;
    float ms[3], mt[3];
    #pragma unroll
    for (int c = 0; c < 3; ++c) { ms[c] = srcS[c] * invN; mt[c] = predS[c] * invN; }

    float S[3][3];
    #pragma unroll
    for (int c = 0; c < 3; ++c)
        #pragma unroll
        for (int d = 0; d < 3; ++d)
            S[c][d] = SP[c * 3 + d] - srcS[c] * predS[d] * invN;

    float A[3][3];
    #pragma unroll
    for (int i = 0; i < 3; ++i)
        #pragma unroll
        for (int j = 0; j < 3; ++j)
            A[i][j] = S[0][i] * S[0][j] + S[1][i] * S[1][j] + S[2][i] * S[2][j];

    float V[3][3] = {{1, 0, 0}, {0, 1, 0}, {0, 0, 1}};
    for (int sweep = 0; sweep < 12; ++sweep) {
        jrot(A, V, 0, 1);
        jrot(A, V, 0, 2);
        jrot(A, V, 1, 2);
    }

    float lam[3] = {A[0][0], A[1][1], A[2][2]};
    for (int i = 0; i < 2; ++i) {
        int mx = i;
        for (int j = i + 1; j < 3; ++j) if (lam[j] > lam[mx]) mx = j;
        if (mx != i) {
            const float tl = lam[i]; lam[i] = lam[mx]; lam[mx] = tl;
            #pragma unroll
            for (int r = 0; r < 3; ++r) {
                const float tv = V[r][i]; V[r][i] = V[r][mx]; V[r][mx] = tv;
            }
        }
    }

    float w0[3], w1[3], u1[3], u2[3], u3[3];
    #pragma unroll
    for (int r = 0; r < 3; ++r) {
        w0[r] = S[r][0] * V[0][0] + S[r][1] * V[1][0] + S[r][2] * V[2][0];
        w1[r] = S[r][0] * V[0][1] + S[r][1] * V[1][1] + S[r][2] * V[2][1];
    }
    const float n1 = sqrtf(w0[0] * w0[0] + w0[1] * w0[1] + w0[2] * w0[2]) + 1e-30f;
    #pragma unroll
    for (int r = 0; r < 3; ++r) u1[r] = w0[r] / n1;
    const float d01 = u1[0] * w1[0] + u1[1] * w1[1] + u1[2] * w1[2];
    #pragma unroll
    for (int r = 0; r < 3; ++r) u2[r] = w1[r] - d01 * u1[r];
    const float n2 = sqrtf(u2[0] * u2[0] + u2[1] * u2[1] + u2[2] * u2[2]) + 1e-30f;
    #pragma unroll
    for (int r = 0; r < 3; ++r) u2[r] /= n2;
    u3[0] = u1[1] * u2[2] - u1[2] * u2[1];
    u3[1] = u1[2] * u2[0] - u1[0] * u2[2];
    u3[2] = u1[0] * u2[1] - u1[1] * u2[0];

    const float detV =
        V[0][0] * (V[1][1] * V[2][2] - V[1][2] * V[2][1]) -
        V[0][1] * (V[1][0] * V[2][2] - V[1][2] * V[2][0]) +
        V[0][2] * (V[1][0] * V[2][1] - V[1][1] * V[2][0]);

    float R[3][3];
    #pragma unroll
    for (int r = 0; r < 3; ++r)
        #pragma unroll
        for (int c = 0; c < 3; ++c)
            R[r][c] = V[r][0] * u1[c] + V[r][1] * u2[c] + detV * V[r][2] * u3[c];

    #pragma unroll
    for (int r = 0; r < 3; ++r)
        #pragma unroll
        for (int c = 0; c < 3; ++c)
            out[b * 9 + r * 3 + c] = R[r][c];

    #pragma unroll
    for (int r = 0; r < 3; ++r) {
        const float tr = mt[r] - (R[r][0] * ms[0] + R[r][1] * ms[1] + R[r][2] * ms[2]);
        out[NB * 9 + b * 3 + r] = tr;
    }
}

extern "C" void kernel_launch(void* const* d_in, const int* in_sizes, int n_in,
                              void* d_out, int out_size, void* d_ws, size_t ws_size,
                              hipStream_t stream)
{
    const float* source  = (const float*)d_in[0];
    const float* target  = (const float*)d_in[1];
    const float* fsource = (const float*)d_in[2];
    const float* ftarget = (const float*)d_in[3];
    float* out = (float*)d_out;

    const size_t PART_FLOATS = (size_t)NB * 16 * 16;
    const size_t ST4_FLOATS  = (size_t)5 * NB * NIQ * NPT;
    const size_t ST2_FLOATS  = (size_t)5 * NB * 2 * NPT;
    const size_t NEED_BIG    = 2 * TPB1 + (ST4_FLOATS + PART_FLOATS) * 4;

    if (ws_size >= NEED_BIG) {
        _Float16* tiled = (_Float16*)d_ws;
        float* stw      = (float*)((char*)d_ws + 2 * TPB1);
        float* partials = stw + ST4_FLOATS;
        prepass_kernel<<<dim3(NB, NKC, 16), 256, 0, stream>>>(fsource, ftarget, tiled);
        attn_state_tiled<<<dim3(NB, 16, NIQ), 256, 0, stream>>>(target, tiled, stw);
        combine4_kernel<<<dim3(NB, 16), 128, 0, stream>>>(source, stw, partials);
        svd_finalize_kernel<<<1, 64, 0, stream>>>(partials, out);
    } else {
        float* stw      = (float*)d_ws;
        float* partials = stw + ST2_FLOATS;
        attn_state_kernel<<<dim3(NB, 8, 2), NTHR, 0, stream>>>(target, fsource, ftarget, stw);
        combine_kernel<<<dim3(NB, 16), 128, 0, stream>>>(source, stw, partials);
        svd_finalize_kernel<<<1, 64, 0, stream>>>(partials, out);
    }
}